// Round 1
// baseline (314.095 us; speedup 1.0000x reference)
//
#include <hip/hip_runtime.h>

#define NTOKEN 50257
#define NTOK_PAD 50304   // 393 * 128
#define DD 256
#define SB 1024
#define C_LOG2PI 235.2482644909f  // 0.5 * 256 * log(2*pi)

typedef __attribute__((ext_vector_type(8))) short bf16x8;
typedef __attribute__((ext_vector_type(4))) float f32x4;

#define MFMA16(a, b, c) __builtin_amdgcn_mfma_f32_16x16x32_bf16((a), (b), (c), 0, 0, 0)

__device__ __forceinline__ unsigned short f2bf(float f) {
  unsigned int u = __float_as_uint(f);
  u += 0x7fffu + ((u >> 16) & 1u);   // round-to-nearest-even
  return (unsigned short)(u >> 16);
}
__device__ __forceinline__ float bf2f(unsigned short s) {
  return __uint_as_float(((unsigned int)s) << 16);
}
__device__ __forceinline__ void gload16(const void* g, void* l) {
  __builtin_amdgcn_global_load_lds(
      (const __attribute__((address_space(1))) unsigned int*)g,
      (__attribute__((address_space(3))) unsigned int*)l, 16, 0, 0);
}

// ---------------- workspace layout (bytes) ----------------
#define HB_OFF   0u                  // 1024*256*2   = 524288
#define ZB_OFF   524288u             // 50304*256*2  = 25755648
#define HN_OFF   26279936u           // 1024*4
#define CB_OFF   26284032u           // 50304*4
#define DM_OFF   26485248u           // 256*4
#define W1B_OFF  26486272u           // 65536*2
#define W2B_OFF  26617344u           // 65536*2  (end = 26748416)

// ---------------- prep kernels ----------------
__global__ __launch_bounds__(256) void prep_h(const float* __restrict__ h,
                                              short* __restrict__ hb,
                                              float* __restrict__ hnorm) {
  int row = blockIdx.x * 256 + threadIdx.x;   // grid 4 -> 1024 rows
  float ss = 0.f;
  #pragma unroll 4
  for (int g = 0; g < 32; ++g) {
    const float4* p = (const float4*)&h[row * 256 + g * 8];
    float4 x = p[0], y = p[1];
    float v[8] = {x.x, x.y, x.z, x.w, y.x, y.y, y.z, y.w};
    bf16x8 o;
    #pragma unroll
    for (int j = 0; j < 8; ++j) { ss += v[j] * v[j]; o[j] = (short)f2bf(v[j]); }
    // pre-swizzled store: 8-elem group index XOR (row&7)
    *(bf16x8*)&hb[row * 256 + ((g ^ (row & 7)) * 8)] = o;
  }
  hnorm[row] = ss;
}

__global__ __launch_bounds__(256) void conv_w(const float* __restrict__ W1x,
                                              const float* __restrict__ W2,
                                              short* __restrict__ W1b,
                                              short* __restrict__ W2b) {
  int base = (blockIdx.x * 256 + threadIdx.x) * 4;  // grid 64 -> 65536 elems
  float4 a = *(const float4*)&W1x[base];
  short4 o1;
  o1.x = (short)f2bf(a.x); o1.y = (short)f2bf(a.y);
  o1.z = (short)f2bf(a.z); o1.w = (short)f2bf(a.w);
  *(short4*)&W1b[base] = o1;
  float4 b = *(const float4*)&W2[base];
  short4 o2;
  o2.x = (short)f2bf(b.x); o2.y = (short)f2bf(b.y);
  o2.z = (short)f2bf(b.z); o2.w = (short)f2bf(b.w);
  *(short4*)&W2b[base] = o2;
}

__global__ __launch_bounds__(256) void diag_k(const float* __restrict__ W1x,
                                              const float* __restrict__ W2,
                                              float* __restrict__ dM) {
  int j = threadIdx.x;  // 1 block x 256
  float s = 0.f;
  for (int i = 0; i < 256; ++i) s += W1x[j * 256 + i] * W2[i * 256 + j];
  dM[j] = s;
}

// ---------------- CNF kernel ----------------
// Per block: 32 tokens. LDS A-tile 32x256 bf16 (XOR-swizzled), 4 waves each
// own a 64-wide N-slice. M-frags m=0..1, N-frags n=0..3, acc f32x4.
__device__ __forceinline__ void mm_tile(const short* __restrict__ A,
                                        const short* __restrict__ B,
                                        int l15, int lane, int wv,
                                        f32x4 acc[2][4]) {
  const f32x4 vzero = {0.f, 0.f, 0.f, 0.f};
  #pragma unroll
  for (int m = 0; m < 2; ++m)
    #pragma unroll
    for (int n = 0; n < 4; ++n) acc[m][n] = vzero;
  const int kof = (lane >> 4) * 8;
  #pragma unroll
  for (int s = 0; s < 8; ++s) {
    int k0 = s * 32 + kof;
    int ks = k0 ^ ((l15 & 7) << 3);               // LDS swizzled k
    bf16x8 a0 = *(const bf16x8*)&A[l15 * 256 + ks];
    bf16x8 a1 = *(const bf16x8*)&A[(16 + l15) * 256 + ks];
    #pragma unroll
    for (int n = 0; n < 4; ++n) {
      const bf16x8 b = *(const bf16x8*)&B[(wv * 64 + n * 16 + l15) * 256 + k0];
      acc[0][n] = MFMA16(a0, b, acc[0][n]);
      acc[1][n] = MFMA16(a1, b, acc[1][n]);
    }
  }
}

__global__ __launch_bounds__(256) void cnf_kernel(
    const float* __restrict__ emb, const short* __restrict__ W1b,
    const short* __restrict__ W2b, const float* __restrict__ dM,
    const float* __restrict__ w1t, const float* __restrict__ b1,
    const float* __restrict__ b2, short* __restrict__ zb,
    float* __restrict__ cbias) {
  __shared__ short At[32 * 256];
  __shared__ short A2[32 * 256];
  __shared__ float trs[32];
  __shared__ float znl[32];
  const int tid = threadIdx.x;
  const int lane = tid & 63;
  const int wv = tid >> 6;
  const int l15 = lane & 15;
  const int rg = (lane >> 4) * 4;
  const int tokbase = blockIdx.x * 32;

  if (tid < 32) trs[tid] = 0.f;

  // ---- stage z0 tile: 8 threads per row, 32 fp32 each ----
  {
    int row = tid >> 3;
    int c0 = (tid & 7) * 32;
    int gtok = tokbase + row;
    float ss = 0.f;
    #pragma unroll
    for (int g = 0; g < 4; ++g) {
      int c = c0 + g * 8;
      float v[8];
      if (gtok < NTOKEN) {
        const float4* p = (const float4*)&emb[(size_t)gtok * 256 + c];
        float4 x = p[0], y = p[1];
        v[0] = x.x; v[1] = x.y; v[2] = x.z; v[3] = x.w;
        v[4] = y.x; v[5] = y.y; v[6] = y.z; v[7] = y.w;
      } else {
        #pragma unroll
        for (int j = 0; j < 8; ++j) v[j] = 0.f;
      }
      bf16x8 o;
      #pragma unroll
      for (int j = 0; j < 8; ++j) { ss += v[j] * v[j]; o[j] = (short)f2bf(v[j]); }
      int blk = (c >> 3) ^ (row & 7);
      *(bf16x8*)&At[row * 256 + blk * 8] = o;
      *(bf16x8*)&zb[(size_t)gtok * 256 + blk * 8] = o;  // pre-swizzled global copy
    }
    ss += __shfl_xor(ss, 1); ss += __shfl_xor(ss, 2); ss += __shfl_xor(ss, 4);
    if ((tid & 7) == 0) znl[row] = ss;
  }
  __syncthreads();

  f32x4 acc[2][4];

  // ---- matmul 1: pre0 = z0 @ W1x^T + b1 (t = 0) ----
  mm_tile(At, W1b, l15, lane, wv, acc);
  {
    float bias[4], dm[4];
    #pragma unroll
    for (int n = 0; n < 4; ++n) {
      int col = wv * 64 + n * 16 + l15;
      bias[n] = b1[col];
      dm[n] = dM[col];
    }
    #pragma unroll
    for (int m = 0; m < 2; ++m)
      #pragma unroll
      for (int r = 0; r < 4; ++r) {
        int trow = m * 16 + rg + r;
        float p = 0.f;
        #pragma unroll
        for (int n = 0; n < 4; ++n) {
          float pre = acc[m][n][r] + bias[n];
          float sg = 1.f / (1.f + __expf(-pre));
          float sp = fmaxf(pre, 0.f) + log1pf(__expf(-fabsf(pre)));
          p += sg * dm[n];
          int col = wv * 64 + n * 16 + l15;
          A2[trow * 256 + (col ^ ((trow & 7) << 3))] = (short)f2bf(sp);
        }
        p += __shfl_xor(p, 1); p += __shfl_xor(p, 2);
        p += __shfl_xor(p, 4); p += __shfl_xor(p, 8);
        if (l15 == 0) atomicAdd(&trs[trow], p);
      }
  }
  __syncthreads();

  // ---- matmul 2: f0 = softplus(pre0) @ W2^T + b2 ; z1 = z0 + 0.5*f0 ----
  mm_tile(A2, W2b, l15, lane, wv, acc);
  {
    float b2v[4];
    #pragma unroll
    for (int n = 0; n < 4; ++n) b2v[n] = b2[wv * 64 + n * 16 + l15];
    #pragma unroll
    for (int m = 0; m < 2; ++m)
      #pragma unroll
      for (int n = 0; n < 4; ++n)
        #pragma unroll
        for (int r = 0; r < 4; ++r) {
          int trow = m * 16 + rg + r;
          int col = wv * 64 + n * 16 + l15;
          int idx = trow * 256 + (col ^ ((trow & 7) << 3));
          float f = acc[m][n][r] + b2v[n];
          float z0v = bf2f((unsigned short)At[idx]);
          At[idx] = (short)f2bf(z0v + 0.5f * f);  // each cell owned by this lane
        }
  }
  __syncthreads();

  // ---- matmul 3: pre1 = z1 @ W1x^T + 0.5*w1t + b1 (t = 0.5) ----
  mm_tile(At, W1b, l15, lane, wv, acc);
  {
    float bias[4], dm[4];
    #pragma unroll
    for (int n = 0; n < 4; ++n) {
      int col = wv * 64 + n * 16 + l15;
      bias[n] = b1[col] + 0.5f * w1t[col];
      dm[n] = dM[col];
    }
    #pragma unroll
    for (int m = 0; m < 2; ++m)
      #pragma unroll
      for (int r = 0; r < 4; ++r) {
        int trow = m * 16 + rg + r;
        float p = 0.f;
        #pragma unroll
        for (int n = 0; n < 4; ++n) {
          float pre = acc[m][n][r] + bias[n];
          float sg = 1.f / (1.f + __expf(-pre));
          p += sg * dm[n];
        }
        p += __shfl_xor(p, 1); p += __shfl_xor(p, 2);
        p += __shfl_xor(p, 4); p += __shfl_xor(p, 8);
        if (l15 == 0) atomicAdd(&trs[trow], p);
      }
  }
  __syncthreads();

  // delta = -0.5*(tr0+tr1); out = log_pz0 - delta  ->  +0.5*trsum
  if (tid < 32)
    cbias[tokbase + tid] = -0.5f * znl[tid] - C_LOG2PI + 0.5f * trs[tid];
}

// ---------------- big log-prob GEMM ----------------
// 128x128 tile, K=256 fully staged (128 KiB LDS), 4 waves in 2x2, each 64x64.
__global__ __launch_bounds__(256) void logp_kernel(
    const short* __restrict__ hb, const short* __restrict__ zb,
    const float* __restrict__ hnorm, const float* __restrict__ cbias,
    float* __restrict__ out) {
  __shared__ short Ah[128 * 256];
  __shared__ short Bz[128 * 256];
  const int tid = threadIdx.x;
  const int lane = tid & 63;
  const int wv = tid >> 6;
  const int l15 = lane & 15;
  const int rg = (lane >> 4) * 4;
  const int bcol = blockIdx.x, brow = blockIdx.y;

  // stage: both tiles are contiguous 64 KiB chunks of pre-swizzled bf16
  const char* asrc = (const char*)(hb + (size_t)brow * 128 * 256);
  const char* bsrc = (const char*)(zb + (size_t)bcol * 128 * 256);
  char* adst = (char*)Ah;
  char* bdst = (char*)Bz;
  #pragma unroll
  for (int it = 0; it < 16; ++it) {
    int uoff = wv * 16384 + it * 1024;   // wave-uniform LDS dest
    int loff = uoff + lane * 16;         // per-lane global src
    gload16(asrc + loff, adst + uoff);
    gload16(bsrc + loff, bdst + uoff);
  }
  __syncthreads();

  const int wr = wv >> 1, wc = wv & 1;
  const f32x4 vzero = {0.f, 0.f, 0.f, 0.f};
  f32x4 acc[4][4];
  #pragma unroll
  for (int m = 0; m < 4; ++m)
    #pragma unroll
    for (int n = 0; n < 4; ++n) acc[m][n] = vzero;

  const int kof = (lane >> 4) * 8;
  #pragma unroll
  for (int s = 0; s < 8; ++s) {
    int k0 = s * 32 + kof;
    int ks = k0 ^ ((l15 & 7) << 3);   // same swizzle for A and B rows
    bf16x8 a[4];
    #pragma unroll
    for (int m = 0; m < 4; ++m)
      a[m] = *(const bf16x8*)&Ah[(wr * 64 + m * 16 + l15) * 256 + ks];
    #pragma unroll
    for (int n = 0; n < 4; ++n) {
      const bf16x8 b = *(const bf16x8*)&Bz[(wc * 64 + n * 16 + l15) * 256 + ks];
      #pragma unroll
      for (int m = 0; m < 4; ++m) acc[m][n] = MFMA16(a[m], b, acc[m][n]);
    }
  }

  // epilogue: out[i,t] = dot - 0.5*hnorm[i] + cbias[t]
  #pragma unroll
  for (int n = 0; n < 4; ++n) {
    int token = bcol * 128 + wc * 64 + n * 16 + l15;
    float cb = cbias[token];
    bool ok = token < NTOKEN;
    #pragma unroll
    for (int m = 0; m < 4; ++m) {
      int i0 = brow * 128 + wr * 64 + m * 16 + rg;
      #pragma unroll
      for (int r = 0; r < 4; ++r) {
        if (ok) {
          float hv = hnorm[i0 + r];
          out[(size_t)(i0 + r) * NTOKEN + token] = acc[m][n][r] - 0.5f * hv + cb;
        }
      }
    }
  }
}

// ---------------- launcher ----------------
extern "C" void kernel_launch(void* const* d_in, const int* in_sizes, int n_in,
                              void* d_out, int out_size, void* d_ws, size_t ws_size,
                              hipStream_t stream) {
  const float* h   = (const float*)d_in[0];
  const float* emb = (const float*)d_in[1];
  const float* W1x = (const float*)d_in[2];
  const float* w1t = (const float*)d_in[3];
  const float* b1  = (const float*)d_in[4];
  const float* W2  = (const float*)d_in[5];
  const float* b2  = (const float*)d_in[6];
  float* out = (float*)d_out;

  char* ws = (char*)d_ws;
  short* hb    = (short*)(ws + HB_OFF);
  short* zb    = (short*)(ws + ZB_OFF);
  float* hnorm = (float*)(ws + HN_OFF);
  float* cbias = (float*)(ws + CB_OFF);
  float* dM    = (float*)(ws + DM_OFF);
  short* W1b   = (short*)(ws + W1B_OFF);
  short* W2b   = (short*)(ws + W2B_OFF);

  prep_h<<<4, 256, 0, stream>>>(h, hb, hnorm);
  conv_w<<<64, 256, 0, stream>>>(W1x, W2, W1b, W2b);
  diag_k<<<1, 256, 0, stream>>>(W1x, W2, dM);
  cnf_kernel<<<NTOK_PAD / 32, 256, 0, stream>>>(emb, W1b, W2b, dM, w1t, b1, b2,
                                                zb, cbias);
  logp_kernel<<<dim3(NTOK_PAD / 128, SB / 128), 256, 0, stream>>>(hb, zb, hnorm,
                                                                  cbias, out);
}